// Round 1
// baseline (704.428 us; speedup 1.0000x reference)
//
#include <hip/hip_runtime.h>
#include <math.h>

// Problem constants
#define BB 32
#define DD 512
#define TT 64
#define RR 49
#define TR 3136      // TT*RR
#define KK 64
#define OUTN 1024
#define KD 32768     // KK*DD

typedef float f4 __attribute__((ext_vector_type(4)));
typedef float f2 __attribute__((ext_vector_type(2)));

// Workspace layout (float offsets)
#define OFF_ASSIGN 0u
#define OFF_ASUM   6422528u          // BB*KK*TR
#define OFF_VLAD   6424576u          // +2048
#define OFF_SROW   7473152u          // +1048576
#define OFF_Y      7475200u          // +2048
// total 7507968 floats = ~28.6 MB

// ---------------------------------------------------------------------------
// Kernel A: logits = conv_w @ x, softmax over k, mask, partial a_sum, store assign
// grid: BB*49 (64-position blocks), block 256
// ---------------------------------------------------------------------------
__global__ __launch_bounds__(256) void kA(const float* __restrict__ x,
                                          const int* __restrict__ mask,
                                          const float* __restrict__ convw,
                                          float* __restrict__ assign,
                                          float* __restrict__ asum) {
    __shared__ float xs[64 * 68];   // [dd][pp] pitch 68
    __shared__ float ws[64 * 68];   // [dd][kk] pitch 68; reused as assign_s [k][p]

    const int blk = blockIdx.x;
    const int b = blk / 49;
    const int pc = blk % 49;
    const int p0 = pc * 64;
    const int tid = threadIdx.x;
    const int pg = tid & 15;        // p-group: p = pg*4 + pi
    const int kg = tid >> 4;        // k-group: k = kg*4 + ki

    float acc[4][4];
#pragma unroll
    for (int i = 0; i < 4; ++i)
#pragma unroll
        for (int j = 0; j < 4; ++j) acc[i][j] = 0.0f;

    const float* xb = x + (size_t)b * DD * TR;

    for (int dc = 0; dc < 8; ++dc) {
        const int d0 = dc * 64;
        __syncthreads();
        // stage x tile [64 d][64 p] : direct copy, float4 over p
#pragma unroll
        for (int i = 0; i < 4; ++i) {
            int lin = i * 256 + tid;
            int dd = lin >> 4;
            int pj = lin & 15;
            f4 v = *(const f4*)(xb + (size_t)(d0 + dd) * TR + p0 + pj * 4);
            *(f4*)(xs + dd * 68 + pj * 4) = v;
        }
        // stage conv_w tile transposed [dd][kk], float4 over d then scatter
#pragma unroll
        for (int i = 0; i < 4; ++i) {
            int lin = i * 256 + tid;
            int kk = lin >> 4;
            int dj = lin & 15;
            f4 v = *(const f4*)(convw + kk * DD + d0 + dj * 4);
#pragma unroll
            for (int j = 0; j < 4; ++j) ws[(dj * 4 + j) * 68 + kk] = v[j];
        }
        __syncthreads();
#pragma unroll 8
        for (int dd = 0; dd < 64; ++dd) {
            f4 xv = *(const f4*)(xs + dd * 68 + pg * 4);
            f4 wv = *(const f4*)(ws + dd * 68 + kg * 4);
#pragma unroll
            for (int ki = 0; ki < 4; ++ki)
#pragma unroll
                for (int pi = 0; pi < 4; ++pi)
                    acc[ki][pi] = fmaf(wv[ki], xv[pi], acc[ki][pi]);
        }
    }
    __syncthreads();
    // dump logits into ws as assign_s[k][p] (pitch 68)
#pragma unroll
    for (int ki = 0; ki < 4; ++ki)
#pragma unroll
        for (int pi = 0; pi < 4; ++pi)
            ws[(kg * 4 + ki) * 68 + (pg * 4 + pi)] = acc[ki][pi];
    __syncthreads();

    // softmax per column p (threads 0..63), then mask
    if (tid < 64) {
        const int p = tid;
        float m = -1e30f;
        for (int k = 0; k < 64; ++k) m = fmaxf(m, ws[k * 68 + p]);
        float s = 0.0f;
        for (int k = 0; k < 64; ++k) {
            float e = expf(ws[k * 68 + p] - m);
            ws[k * 68 + p] = e;
            s += e;
        }
        const int t = (p0 + p) / RR;
        const float mk = (float)mask[b * TT + t];
        const float inv = mk / s;
        for (int k = 0; k < 64; ++k) ws[k * 68 + p] *= inv;
    }
    __syncthreads();

    // partial a_sum (threads 0..63, one k each)
    if (tid < 64) {
        const int k = tid;
        float s = 0.0f;
        for (int p = 0; p < 64; ++p) s += ws[k * 68 + p];
        atomicAdd(&asum[b * 64 + k], s);
    }
    // store assign[b][k][p] (float4 over p)
#pragma unroll
    for (int i = 0; i < 4; ++i) {
        int lin = i * 256 + tid;
        int kk = lin >> 4;
        int pj = lin & 15;
        f4 v = *(const f4*)(ws + kk * 68 + pj * 4);
        *(f4*)(assign + (size_t)(b * 64 + kk) * TR + p0 + pj * 4) = v;
    }
}

// ---------------------------------------------------------------------------
// Kernel B: vlad[b,k,d] = sum_p assign[b,k,p]*x[b,d,p] - a_sum[b,k]*c[k,d]
// grid: BB*16 (32-wide d slices), block 256
// ---------------------------------------------------------------------------
__global__ __launch_bounds__(256) void kB(const float* __restrict__ x,
                                          const float* __restrict__ assign,
                                          const float* __restrict__ asum,
                                          const float* __restrict__ cent,
                                          float* __restrict__ vlad) {
    __shared__ float as_t[64 * 68];  // [p][k] pitch 68
    __shared__ float xs_t[64 * 36];  // [p][dl] pitch 36 (32 d + pad)

    const int blk = blockIdx.x;
    const int b = blk >> 4;
    const int db = blk & 15;
    const int d0 = db * 32;
    const int tid = threadIdx.x;
    const int kg = tid & 15;   // k = kg*4 + ki
    const int dg = tid >> 4;   // d = d0 + dg*2 + di

    float acc[4][2];
#pragma unroll
    for (int i = 0; i < 4; ++i) { acc[i][0] = 0.0f; acc[i][1] = 0.0f; }

    const float* xb = x + (size_t)b * DD * TR;
    const float* ab = assign + (size_t)b * KK * TR;

    for (int pc = 0; pc < 49; ++pc) {
        const int p0 = pc * 64;
        __syncthreads();
        // assign tile 64k x 64p -> transposed [p][k]
#pragma unroll
        for (int i = 0; i < 4; ++i) {
            int lin = i * 256 + tid;
            int kk = lin >> 4;
            int pj = lin & 15;
            f4 v = *(const f4*)(ab + (size_t)kk * TR + p0 + pj * 4);
#pragma unroll
            for (int j = 0; j < 4; ++j) as_t[(pj * 4 + j) * 68 + kk] = v[j];
        }
        // x tile 32d x 64p -> transposed [p][dl]
#pragma unroll
        for (int i = 0; i < 2; ++i) {
            int lin = i * 256 + tid;
            int dl = lin >> 4;
            int pj = lin & 15;
            f4 v = *(const f4*)(xb + (size_t)(d0 + dl) * TR + p0 + pj * 4);
#pragma unroll
            for (int j = 0; j < 4; ++j) xs_t[(pj * 4 + j) * 36 + dl] = v[j];
        }
        __syncthreads();
#pragma unroll 8
        for (int pp = 0; pp < 64; ++pp) {
            f4 av = *(const f4*)(as_t + pp * 68 + kg * 4);
            f2 xv = *(const f2*)(xs_t + pp * 36 + dg * 2);
#pragma unroll
            for (int ki = 0; ki < 4; ++ki) {
                acc[ki][0] = fmaf(av[ki], xv[0], acc[ki][0]);
                acc[ki][1] = fmaf(av[ki], xv[1], acc[ki][1]);
            }
        }
    }
    // epilogue: subtract a_sum*centroid, store
#pragma unroll
    for (int ki = 0; ki < 4; ++ki) {
        const int k = kg * 4 + ki;
        const float asv = asum[b * 64 + k];
        const int d = d0 + dg * 2;
        f2 cv = *(const f2*)(cent + k * DD + d);
        f2 ov;
        ov[0] = acc[ki][0] - asv * cv[0];
        ov[1] = acc[ki][1] - asv * cv[1];
        *(f2*)(vlad + (size_t)b * KD + k * DD + d) = ov;
    }
}

// ---------------------------------------------------------------------------
// Kernel C: per-row intra norms + global norm -> per-row scale srow[b,k]
// grid: BB, block 256
// ---------------------------------------------------------------------------
__global__ __launch_bounds__(256) void kC(const float* __restrict__ vlad,
                                          float* __restrict__ srow) {
    __shared__ float rn[64];
    __shared__ float cb[64];
    __shared__ float inv_s[64];
    __shared__ float gval;

    const int b = blockIdx.x;
    const int tid = threadIdx.x;
    const int wave = tid >> 6;
    const int lane = tid & 63;
    const float* vb = vlad + (size_t)b * KD;

    for (int k = wave; k < 64; k += 4) {
        float s = 0.0f;
#pragma unroll
        for (int i = 0; i < 8; ++i) {
            float v = vb[k * DD + lane + i * 64];
            s = fmaf(v, v, s);
        }
        for (int off = 32; off > 0; off >>= 1) s += __shfl_down(s, off, 64);
        if (lane == 0) rn[k] = s;
    }
    __syncthreads();
    if (tid < 64) {
        float n = sqrtf(rn[tid]);
        float inv = 1.0f / fmaxf(n, 1e-12f);
        inv_s[tid] = inv;
        cb[tid] = rn[tid] * inv * inv;
    }
    __syncthreads();
    if (tid == 0) {
        float g = 0.0f;
        for (int k = 0; k < 64; ++k) g += cb[k];
        g = sqrtf(g);
        gval = 1.0f / fmaxf(g, 1e-12f);
    }
    __syncthreads();
    if (tid < 64) srow[b * 64 + tid] = inv_s[tid] * gval;
}

// ---------------------------------------------------------------------------
// Kernel D: y[b,o] += sum_j srow[b,j/512]*vlad[b,j]*red_w[o,j]
// grid: 16 o-tiles * 32 j-splits, block 256
// ---------------------------------------------------------------------------
__global__ __launch_bounds__(256) void kD(const float* __restrict__ vlad,
                                          const float* __restrict__ srow,
                                          const float* __restrict__ redw,
                                          float* __restrict__ y) {
    __shared__ float rw_t[64 * 68];  // [j][o] pitch 68
    __shared__ float vs_t[64 * 36];  // [j][b] pitch 36

    const int blk = blockIdx.x;
    const int ot = blk & 15;
    const int js = blk >> 4;
    const int o0 = ot * 64;
    const int jbase = js * 1024;
    const int tid = threadIdx.x;
    const int og = tid & 15;   // o = o0 + og*4 + oi
    const int bg = tid >> 4;   // b = bg*2 + bi

    float acc[4][2];
#pragma unroll
    for (int i = 0; i < 4; ++i) { acc[i][0] = 0.0f; acc[i][1] = 0.0f; }

    for (int jc = 0; jc < 16; ++jc) {
        const int j0 = jbase + jc * 64;
        __syncthreads();
#pragma unroll
        for (int i = 0; i < 4; ++i) {
            int lin = i * 256 + tid;
            int oo = lin >> 4;
            int pj = lin & 15;
            f4 v = *(const f4*)(redw + (size_t)(o0 + oo) * KD + j0 + pj * 4);
#pragma unroll
            for (int j = 0; j < 4; ++j) rw_t[(pj * 4 + j) * 68 + oo] = v[j];
        }
#pragma unroll
        for (int i = 0; i < 2; ++i) {
            int lin = i * 256 + tid;
            int bb = lin >> 4;
            int pj = lin & 15;
            int j = j0 + pj * 4;
            float sc = srow[bb * 64 + (j >> 9)];
            f4 v = *(const f4*)(vlad + (size_t)bb * KD + j);
#pragma unroll
            for (int jj = 0; jj < 4; ++jj) vs_t[(pj * 4 + jj) * 36 + bb] = v[jj] * sc;
        }
        __syncthreads();
#pragma unroll 8
        for (int jj = 0; jj < 64; ++jj) {
            f4 rv = *(const f4*)(rw_t + jj * 68 + og * 4);
            f2 vv = *(const f2*)(vs_t + jj * 36 + bg * 2);
#pragma unroll
            for (int oi = 0; oi < 4; ++oi) {
                acc[oi][0] = fmaf(rv[oi], vv[0], acc[oi][0]);
                acc[oi][1] = fmaf(rv[oi], vv[1], acc[oi][1]);
            }
        }
    }
#pragma unroll
    for (int oi = 0; oi < 4; ++oi)
#pragma unroll
        for (int bi = 0; bi < 2; ++bi)
            atomicAdd(&y[(size_t)(bg * 2 + bi) * OUTN + o0 + og * 4 + oi], acc[oi][bi]);
}

// ---------------------------------------------------------------------------
// Kernel E: LayerNorm over OUT per b -> d_out
// grid: BB, block 256
// ---------------------------------------------------------------------------
__global__ __launch_bounds__(256) void kE(const float* __restrict__ y,
                                          const float* __restrict__ gamma,
                                          const float* __restrict__ beta,
                                          float* __restrict__ out) {
    __shared__ float s1s[4], s2s[4];
    __shared__ float mu_s, rstd_s;

    const int b = blockIdx.x;
    const int tid = threadIdx.x;
    const int wave = tid >> 6;
    const int lane = tid & 63;

    f4 v = *(const f4*)(y + (size_t)b * OUTN + tid * 4);
    float s1 = v[0] + v[1] + v[2] + v[3];
    float s2 = v[0] * v[0] + v[1] * v[1] + v[2] * v[2] + v[3] * v[3];
    for (int off = 32; off > 0; off >>= 1) {
        s1 += __shfl_down(s1, off, 64);
        s2 += __shfl_down(s2, off, 64);
    }
    if (lane == 0) { s1s[wave] = s1; s2s[wave] = s2; }
    __syncthreads();
    if (tid == 0) {
        float S1 = s1s[0] + s1s[1] + s1s[2] + s1s[3];
        float S2 = s2s[0] + s2s[1] + s2s[2] + s2s[3];
        float mu = S1 / (float)OUTN;
        float var = S2 / (float)OUTN - mu * mu;
        mu_s = mu;
        rstd_s = 1.0f / sqrtf(var + 1e-5f);
    }
    __syncthreads();
    const float mu = mu_s, rstd = rstd_s;
    f4 g = *(const f4*)(gamma + tid * 4);
    f4 be = *(const f4*)(beta + tid * 4);
    f4 o;
#pragma unroll
    for (int i = 0; i < 4; ++i) o[i] = (v[i] - mu) * rstd * g[i] + be[i];
    *(f4*)(out + (size_t)b * OUTN + tid * 4) = o;
}

// ---------------------------------------------------------------------------
extern "C" void kernel_launch(void* const* d_in, const int* in_sizes, int n_in,
                              void* d_out, int out_size, void* d_ws, size_t ws_size,
                              hipStream_t stream) {
    const float* x     = (const float*)d_in[0];
    const int*   mask  = (const int*)d_in[1];
    const float* cent  = (const float*)d_in[2];
    const float* convw = (const float*)d_in[3];
    const float* redw  = (const float*)d_in[4];
    const float* gam   = (const float*)d_in[5];
    const float* bet   = (const float*)d_in[6];
    float* out = (float*)d_out;
    float* w = (float*)d_ws;

    float* assign = w + OFF_ASSIGN;
    float* asum   = w + OFF_ASUM;
    float* vlad   = w + OFF_VLAD;
    float* srow   = w + OFF_SROW;
    float* y      = w + OFF_Y;

    hipMemsetAsync(asum, 0, 2048 * sizeof(float), stream);
    hipMemsetAsync(y, 0, 32768 * sizeof(float), stream);

    kA<<<BB * 49, 256, 0, stream>>>(x, mask, convw, assign, asum);
    kB<<<BB * 16, 256, 0, stream>>>(x, assign, asum, cent, vlad);
    kC<<<BB, 256, 0, stream>>>(vlad, srow);
    kD<<<16 * 32, 256, 0, stream>>>(vlad, srow, redw, y);
    kE<<<BB, 256, 0, stream>>>(y, gam, bet, out);
}

// Round 2
// 528.043 us; speedup vs baseline: 1.3340x; 1.3340x over previous
//
#include <hip/hip_runtime.h>
#include <math.h>

// Problem constants
#define BB 32
#define DD 512
#define TT 64
#define RR 49
#define TR 3136      // TT*RR
#define KK 64
#define OUTN 1024
#define KD 32768     // KK*DD

typedef float f4 __attribute__((ext_vector_type(4)));
typedef short s8 __attribute__((ext_vector_type(8)));

// Workspace layout (byte offsets, all 256-aligned)
#define OFF_ASSIGN 0ull          // bf16 assign [32][64][3136]  = 12,845,056 B
#define OFF_VLADP  12845056ull   // fp32 vladP [2][32][64][512] =  8,388,608 B
#define OFF_VN     21233664ull   // bf16 vlad_n [32][32768]     =  2,097,152 B
#define OFF_SS     23330816ull   // fp32 ss [32][64]            =      8,192 B
#define OFF_ASUM   23339008ull   // fp32 asum [32][64]          =      8,192 B
#define OFF_Y      23347200ull   // fp32 y [32][1024]           =    131,072 B
// end: 23,478,272 B (~22.4 MB)

__device__ __forceinline__ unsigned short bf16c(float f) {
    union { float f; unsigned u; } v; v.f = f;
    unsigned r = v.u + 0x7FFFu + ((v.u >> 16) & 1u);  // RNE
    return (unsigned short)(r >> 16);
}

__device__ __forceinline__ unsigned long long pack4(float a, float b, float c, float d) {
    unsigned lo = (unsigned)bf16c(a) | ((unsigned)bf16c(b) << 16);
    unsigned hi = (unsigned)bf16c(c) | ((unsigned)bf16c(d) << 16);
    return (unsigned long long)lo | ((unsigned long long)hi << 32);
}

// ---------------------------------------------------------------------------
// kA: logits = conv_w @ x (MFMA bf16), softmax over k, mask, asum, assign(bf16)
// grid 32*49, block 256. Per block: 64 k x 64 p, K-loop over d=512.
// ---------------------------------------------------------------------------
__global__ __launch_bounds__(256) void kA(const float* __restrict__ x,
                                          const int* __restrict__ mask,
                                          const float* __restrict__ convw,
                                          unsigned short* __restrict__ assign,
                                          float* __restrict__ asum) {
    __shared__ unsigned short cw_l[64 * 136];  // [k][d-chunk 128 + pad]
    __shared__ unsigned short xT_l[64 * 136];  // [p][d-chunk 128 + pad]
    __shared__ float sm[64 * 68];              // [k][p] logits/assign

    const int blk = blockIdx.x;
    const int b = blk / 49;
    const int pc = blk % 49;
    const int p0 = pc * 64;
    const int tid = threadIdx.x;
    const int lane = tid & 63;
    const int wv = tid >> 6;
    const int quad = lane >> 4;
    const int l15 = lane & 15;

    f4 acc[4];
#pragma unroll
    for (int t = 0; t < 4; ++t) acc[t] = (f4){0.f, 0.f, 0.f, 0.f};

    const float* xb = x + (size_t)b * DD * TR;

    for (int dc = 0; dc < 4; ++dc) {
        const int d0 = dc * 128;
        __syncthreads();
        // stage conv_w chunk [64 k][128 d] -> bf16, row-contiguous
#pragma unroll
        for (int i = 0; i < 8; ++i) {
            int lin = i * 256 + tid;
            int row = lin >> 5;
            int c = lin & 31;
            f4 v = *(const f4*)(convw + row * DD + d0 + c * 4);
            *(unsigned long long*)(cw_l + row * 136 + c * 4) = pack4(v[0], v[1], v[2], v[3]);
        }
        // stage x chunk transposed [64 p][128 d]: thread = (d-quad, p-quad)
#pragma unroll
        for (int i = 0; i < 2; ++i) {
            int lin = i * 256 + tid;
            int dq = lin >> 4;   // 0..31 -> d = d0 + dq*4
            int pq = lin & 15;
            const float* xp = xb + (size_t)(d0 + dq * 4) * TR + p0 + pq * 4;
            f4 a0 = *(const f4*)(xp);
            f4 a1 = *(const f4*)(xp + TR);
            f4 a2 = *(const f4*)(xp + 2 * TR);
            f4 a3 = *(const f4*)(xp + 3 * TR);
#pragma unroll
            for (int jj = 0; jj < 4; ++jj) {
                int j = (jj + pq) & 3;  // stagger to spread banks
                *(unsigned long long*)(xT_l + (pq * 4 + j) * 136 + dq * 4) =
                    pack4(a0[j], a1[j], a2[j], a3[j]);
            }
        }
        __syncthreads();
#pragma unroll
        for (int ks = 0; ks < 4; ++ks) {
            int off = ks * 32 + quad * 8;
            s8 af = *(const s8*)(cw_l + (wv * 16 + l15) * 136 + off);
#pragma unroll
            for (int t = 0; t < 4; ++t) {
                s8 bfr = *(const s8*)(xT_l + (t * 16 + l15) * 136 + off);
                acc[t] = __builtin_amdgcn_mfma_f32_16x16x32_bf16(af, bfr, acc[t], 0, 0, 0);
            }
        }
    }
    __syncthreads();
    // dump C/D frags to sm[k][p]: col=lane&15 (p), row=quad*4+reg (k)
#pragma unroll
    for (int t = 0; t < 4; ++t)
#pragma unroll
        for (int r = 0; r < 4; ++r)
            sm[(wv * 16 + quad * 4 + r) * 68 + t * 16 + l15] = acc[t][r];
    __syncthreads();
    // softmax over k per column p, then mask
    if (tid < 64) {
        const int p = tid;
        float mx = -1e30f;
        for (int k = 0; k < 64; ++k) mx = fmaxf(mx, sm[k * 68 + p]);
        float s = 0.f;
        for (int k = 0; k < 64; ++k) {
            float e = __expf(sm[k * 68 + p] - mx);
            sm[k * 68 + p] = e;
            s += e;
        }
        const int t = (p0 + p) / RR;
        const float inv = (float)mask[b * TT + t] / s;
        for (int k = 0; k < 64; ++k) sm[k * 68 + p] *= inv;
    }
    __syncthreads();
    // partial a_sum per k
    if (tid < 64) {
        const int k = tid;
        float s = 0.f;
#pragma unroll
        for (int i = 0; i < 16; ++i) {
            f4 v = *(const f4*)(sm + k * 68 + i * 4);
            s += v[0] + v[1] + v[2] + v[3];
        }
        atomicAdd(&asum[b * 64 + k], s);
    }
    // write assign bf16 [k][p]
#pragma unroll
    for (int i = 0; i < 4; ++i) {
        int lin = i * 256 + tid;
        int kr = lin >> 4;
        int pq = lin & 15;
        f4 v = *(const f4*)(sm + kr * 68 + pq * 4);
        *(unsigned long long*)(assign + (size_t)(b * 64 + kr) * TR + p0 + pq * 4) =
            pack4(v[0], v[1], v[2], v[3]);
    }
}

// ---------------------------------------------------------------------------
// kB: vladP[ph][b,k,d] = sum_{p in half} assign[k][p]*x[d][p]  (MFMA bf16)
// part 0 additionally subtracts asum*centroid. grid 32*8*2, block 256.
// ---------------------------------------------------------------------------
__global__ __launch_bounds__(256) void kB(const float* __restrict__ x,
                                          const unsigned short* __restrict__ assign,
                                          const float* __restrict__ asum,
                                          const float* __restrict__ cent,
                                          float* __restrict__ vladP) {
    __shared__ unsigned short as_l[64 * 72];  // [k][p-chunk 64 + pad]
    __shared__ unsigned short x_l[64 * 72];   // [d][p-chunk 64 + pad]

    const int blk = blockIdx.x;
    const int b = blk >> 4;
    const int ds = (blk >> 1) & 7;
    const int ph = blk & 1;
    const int d0 = ds * 64;
    const int tid = threadIdx.x;
    const int lane = tid & 63;
    const int wv = tid >> 6;
    const int quad = lane >> 4;
    const int l15 = lane & 15;

    f4 acc[4];
#pragma unroll
    for (int t = 0; t < 4; ++t) acc[t] = (f4){0.f, 0.f, 0.f, 0.f};

    const int pcs = ph ? 25 : 0;
    const int pce = ph ? 49 : 25;
    for (int pc = pcs; pc < pce; ++pc) {
        const int p0 = pc * 64;
        __syncthreads();
        // assign (already bf16): direct 16B copies
#pragma unroll
        for (int i = 0; i < 2; ++i) {
            int lin = i * 256 + tid;
            int row = lin >> 3;
            int c = lin & 7;
            *(s8*)(as_l + row * 72 + c * 8) =
                *(const s8*)(assign + (size_t)(b * 64 + row) * TR + p0 + c * 8);
        }
        // x fp32 -> bf16, natural [d][p]
#pragma unroll
        for (int i = 0; i < 4; ++i) {
            int lin = i * 256 + tid;
            int row = lin >> 4;
            int c = lin & 15;
            f4 v = *(const f4*)(x + (size_t)(b * DD + d0 + row) * TR + p0 + c * 4);
            *(unsigned long long*)(x_l + row * 72 + c * 4) = pack4(v[0], v[1], v[2], v[3]);
        }
        __syncthreads();
#pragma unroll
        for (int ks = 0; ks < 2; ++ks) {
            int off = ks * 32 + quad * 8;
            s8 af = *(const s8*)(as_l + (wv * 16 + l15) * 72 + off);
#pragma unroll
            for (int t = 0; t < 4; ++t) {
                s8 bfr = *(const s8*)(x_l + (t * 16 + l15) * 72 + off);
                acc[t] = __builtin_amdgcn_mfma_f32_16x16x32_bf16(af, bfr, acc[t], 0, 0, 0);
            }
        }
    }
    float* vp = vladP + (size_t)ph * (BB * KK * DD);
#pragma unroll
    for (int r = 0; r < 4; ++r) {
        const int k = wv * 16 + quad * 4 + r;
        float corr = ph ? 0.f : asum[b * 64 + k];
#pragma unroll
        for (int t = 0; t < 4; ++t) {
            const int d = d0 + t * 16 + l15;
            float v = acc[t][r];
            if (!ph) v -= corr * cent[k * DD + d];
            vp[(size_t)(b * 64 + k) * DD + d] = v;
        }
    }
}

// ---------------------------------------------------------------------------
// kC1: per-row sum of squares of (P0+P1). grid 32*8, block 256 (8 rows x 32 thr)
// ---------------------------------------------------------------------------
__global__ __launch_bounds__(256) void kC1(const float* __restrict__ vladP,
                                           float* __restrict__ ss) {
    const int blk = blockIdx.x;
    const int b = blk >> 3;
    const int ks = blk & 7;
    const int tid = threadIdx.x;
    const int kr = tid >> 5;
    const int l32 = tid & 31;
    const int k = ks * 8 + kr;
    const float* q0 = vladP + (size_t)(b * 64 + k) * DD;
    const float* q1 = q0 + (size_t)BB * KK * DD;
    float s = 0.f;
#pragma unroll
    for (int i = 0; i < 4; ++i) {
        f4 a = *(const f4*)(q0 + i * 128 + l32 * 4);
        f4 c = *(const f4*)(q1 + i * 128 + l32 * 4);
#pragma unroll
        for (int j = 0; j < 4; ++j) { float v = a[j] + c[j]; s = fmaf(v, v, s); }
    }
    for (int off = 16; off > 0; off >>= 1) s += __shfl_down(s, off, 32);
    if (l32 == 0) ss[b * 64 + k] = s;
}

// ---------------------------------------------------------------------------
// kC2: scales = intra*global norm; write vlad_n bf16. grid 32*8, block 256.
// ---------------------------------------------------------------------------
__global__ __launch_bounds__(256) void kC2(const float* __restrict__ vladP,
                                           const float* __restrict__ ss,
                                           unsigned short* __restrict__ vn) {
    __shared__ float sc[64];
    const int blk = blockIdx.x;
    const int b = blk >> 3;
    const int js = blk & 7;
    const int tid = threadIdx.x;
    if (tid < 64) {
        float rn = sqrtf(ss[b * 64 + tid]);
        float inv = 1.f / fmaxf(rn, 1e-12f);
        float cb = rn * inv; cb = cb * cb;
        float g = cb;
        for (int off = 32; off > 0; off >>= 1) g += __shfl_down(g, off, 64);
        g = __shfl(g, 0, 64);
        float gi = 1.f / fmaxf(sqrtf(g), 1e-12f);
        sc[tid] = inv * gi;
    }
    __syncthreads();
    const float* q0 = vladP + (size_t)b * KD;
    const float* q1 = q0 + (size_t)BB * KD;
#pragma unroll
    for (int it = 0; it < 4; ++it) {
        int j = js * 4096 + it * 1024 + tid * 4;
        f4 a = *(const f4*)(q0 + j);
        f4 c = *(const f4*)(q1 + j);
        float scl = sc[j >> 9];
        *(unsigned long long*)(vn + (size_t)b * KD + j) =
            pack4((a[0] + c[0]) * scl, (a[1] + c[1]) * scl,
                  (a[2] + c[2]) * scl, (a[3] + c[3]) * scl);
    }
}

// ---------------------------------------------------------------------------
// kD: y[b,o] += vlad_n @ red_w^T (MFMA bf16, red_w converted in staging)
// grid 16 o-tiles * 16 j-splits, block 256. atomicAdd fp32 into y.
// ---------------------------------------------------------------------------
__global__ __launch_bounds__(256) void kD(const unsigned short* __restrict__ vn,
                                          const float* __restrict__ redw,
                                          float* __restrict__ y) {
    __shared__ unsigned short rw_l[64 * 264];  // [o][j-chunk 256 + pad]
    __shared__ unsigned short vl_l[32 * 264];  // [b][j-chunk 256 + pad]

    const int blk = blockIdx.x;
    const int ot = blk & 15;
    const int js = blk >> 4;
    const int o0 = ot * 64;
    const int jb = js * 2048;
    const int tid = threadIdx.x;
    const int lane = tid & 63;
    const int wv = tid >> 6;
    const int quad = lane >> 4;
    const int l15 = lane & 15;

    f4 acc[2];
    acc[0] = (f4){0.f, 0.f, 0.f, 0.f};
    acc[1] = (f4){0.f, 0.f, 0.f, 0.f};

    for (int jc = 0; jc < 8; ++jc) {
        const int j0 = jb + jc * 256;
        __syncthreads();
#pragma unroll
        for (int i = 0; i < 16; ++i) {
            int lin = i * 256 + tid;
            int row = lin >> 6;
            int c = lin & 63;
            f4 v = *(const f4*)(redw + (size_t)(o0 + row) * KD + j0 + c * 4);
            *(unsigned long long*)(rw_l + row * 264 + c * 4) = pack4(v[0], v[1], v[2], v[3]);
        }
#pragma unroll
        for (int i = 0; i < 4; ++i) {
            int lin = i * 256 + tid;
            int row = lin >> 5;
            int c = lin & 31;
            *(s8*)(vl_l + row * 264 + c * 8) =
                *(const s8*)(vn + (size_t)row * KD + j0 + c * 8);
        }
        __syncthreads();
#pragma unroll
        for (int ks = 0; ks < 8; ++ks) {
            int off = ks * 32 + quad * 8;
            s8 bfr = *(const s8*)(rw_l + (wv * 16 + l15) * 264 + off);
#pragma unroll
            for (int t = 0; t < 2; ++t) {
                s8 af = *(const s8*)(vl_l + (t * 16 + l15) * 264 + off);
                acc[t] = __builtin_amdgcn_mfma_f32_16x16x32_bf16(af, bfr, acc[t], 0, 0, 0);
            }
        }
    }
#pragma unroll
    for (int t = 0; t < 2; ++t)
#pragma unroll
        for (int r = 0; r < 4; ++r) {
            int bq = t * 16 + quad * 4 + r;
            int o = o0 + wv * 16 + l15;
            atomicAdd(&y[(size_t)bq * OUTN + o], acc[t][r]);
        }
}

// ---------------------------------------------------------------------------
// kE: LayerNorm over OUT per b -> d_out. grid 32, block 256.
// ---------------------------------------------------------------------------
__global__ __launch_bounds__(256) void kE(const float* __restrict__ y,
                                          const float* __restrict__ gamma,
                                          const float* __restrict__ beta,
                                          float* __restrict__ out) {
    __shared__ float s1s[4], s2s[4];
    __shared__ float mu_s, rstd_s;

    const int b = blockIdx.x;
    const int tid = threadIdx.x;
    const int wave = tid >> 6;
    const int lane = tid & 63;

    f4 v = *(const f4*)(y + (size_t)b * OUTN + tid * 4);
    float s1 = v[0] + v[1] + v[2] + v[3];
    float s2 = v[0] * v[0] + v[1] * v[1] + v[2] * v[2] + v[3] * v[3];
    for (int off = 32; off > 0; off >>= 1) {
        s1 += __shfl_down(s1, off, 64);
        s2 += __shfl_down(s2, off, 64);
    }
    if (lane == 0) { s1s[wave] = s1; s2s[wave] = s2; }
    __syncthreads();
    if (tid == 0) {
        float S1 = s1s[0] + s1s[1] + s1s[2] + s1s[3];
        float S2 = s2s[0] + s2s[1] + s2s[2] + s2s[3];
        float mu = S1 / (float)OUTN;
        float var = S2 / (float)OUTN - mu * mu;
        mu_s = mu;
        rstd_s = 1.0f / sqrtf(var + 1e-5f);
    }
    __syncthreads();
    const float mu = mu_s, rstd = rstd_s;
    f4 g = *(const f4*)(gamma + tid * 4);
    f4 be = *(const f4*)(beta + tid * 4);
    f4 o;
#pragma unroll
    for (int i = 0; i < 4; ++i) o[i] = (v[i] - mu) * rstd * g[i] + be[i];
    *(f4*)(out + (size_t)b * OUTN + tid * 4) = o;
}

// ---------------------------------------------------------------------------
extern "C" void kernel_launch(void* const* d_in, const int* in_sizes, int n_in,
                              void* d_out, int out_size, void* d_ws, size_t ws_size,
                              hipStream_t stream) {
    const float* x     = (const float*)d_in[0];
    const int*   mask  = (const int*)d_in[1];
    const float* cent  = (const float*)d_in[2];
    const float* convw = (const float*)d_in[3];
    const float* redw  = (const float*)d_in[4];
    const float* gam   = (const float*)d_in[5];
    const float* bet   = (const float*)d_in[6];
    float* out = (float*)d_out;
    char* w = (char*)d_ws;

    unsigned short* assign = (unsigned short*)(w + OFF_ASSIGN);
    float*          vladP  = (float*)(w + OFF_VLADP);
    unsigned short* vn     = (unsigned short*)(w + OFF_VN);
    float*          ss     = (float*)(w + OFF_SS);
    float*          asum   = (float*)(w + OFF_ASUM);
    float*          y      = (float*)(w + OFF_Y);

    hipMemsetAsync(asum, 0, 64 * BB * sizeof(float), stream);
    hipMemsetAsync(y, 0, BB * OUTN * sizeof(float), stream);

    kA<<<BB * 49, 256, 0, stream>>>(x, mask, convw, assign, asum);
    kB<<<BB * 8 * 2, 256, 0, stream>>>(x, assign, asum, cent, vladP);
    kC1<<<BB * 8, 256, 0, stream>>>(vladP, ss);
    kC2<<<BB * 8, 256, 0, stream>>>(vladP, ss, vn);
    kD<<<16 * 16, 256, 0, stream>>>(vn, redw, y);
    kE<<<BB, 256, 0, stream>>>(y, gam, bet, out);
}

// Round 3
// 479.931 us; speedup vs baseline: 1.4678x; 1.1002x over previous
//
#include <hip/hip_runtime.h>
#include <math.h>

// Problem constants
#define BB 32
#define DD 512
#define TT 64
#define RR 49
#define TR 3136      // TT*RR
#define KK 64
#define OUTN 1024
#define KD 32768     // KK*DD

typedef float f4 __attribute__((ext_vector_type(4)));
typedef short s8 __attribute__((ext_vector_type(8)));

// Workspace layout (byte offsets, all 256-aligned)
#define OFF_ASSIGN 0ull          // bf16 assign [32][64][3136]  = 12,845,056 B
#define OFF_VLADP  12845056ull   // fp32 vladP [2][32][64][512] =  8,388,608 B
#define OFF_VN     21233664ull   // bf16 vlad_n [32][32768]     =  2,097,152 B
#define OFF_SS     23330816ull   // fp32 ss [32][64]            =      8,192 B
#define OFF_ASUM   23339008ull   // fp32 asum [32][64]          =      8,192 B
#define OFF_Y      23347200ull   // fp32 y [32][1024]           =    131,072 B
// end: 23,478,272 B (~22.4 MB)

// Cheap fp32->bf16 pack: round-half-up (+0x8000 on bits) then v_perm high-half
// pack. 6 VALU ops per 4 elements vs ~20 for full RNE emulation.
__device__ __forceinline__ unsigned long long pack4(float a, float b, float c, float d) {
    union { float f; unsigned u; } A, B, C, D;
    A.f = a; B.f = b; C.f = c; D.f = d;
    unsigned lo = __builtin_amdgcn_perm(B.u + 0x8000u, A.u + 0x8000u, 0x07060302u);
    unsigned hi = __builtin_amdgcn_perm(D.u + 0x8000u, C.u + 0x8000u, 0x07060302u);
    return (unsigned long long)lo | ((unsigned long long)hi << 32);
}

// ---------------------------------------------------------------------------
// kA: logits = conv_w @ x (MFMA bf16), softmax over k, mask, asum, assign(bf16)
// grid 32*49, block 256. Per block: 64 k x 64 p, K-loop over d=512.
// ---------------------------------------------------------------------------
__global__ __launch_bounds__(256) void kA(const float* __restrict__ x,
                                          const int* __restrict__ mask,
                                          const float* __restrict__ convw,
                                          unsigned short* __restrict__ assign,
                                          float* __restrict__ asum) {
    __shared__ unsigned short cw_l[64 * 136];  // [k][d-chunk 128 + pad]; reused as red buf
    __shared__ unsigned short xT_l[64 * 136];  // [p][d-chunk 128 + pad]
    __shared__ float sm[64 * 68];              // [k][p] logits/assign

    const int blk = blockIdx.x;
    const int b = blk / 49;
    const int pc = blk % 49;
    const int p0 = pc * 64;
    const int tid = threadIdx.x;
    const int lane = tid & 63;
    const int wv = tid >> 6;
    const int quad = lane >> 4;
    const int l15 = lane & 15;

    f4 acc[4];
#pragma unroll
    for (int t = 0; t < 4; ++t) acc[t] = (f4){0.f, 0.f, 0.f, 0.f};

    const float* xb = x + (size_t)b * DD * TR;

    for (int dc = 0; dc < 4; ++dc) {
        const int d0 = dc * 128;
        __syncthreads();
        // stage conv_w chunk [64 k][128 d] -> bf16, row-contiguous
#pragma unroll
        for (int i = 0; i < 8; ++i) {
            int lin = i * 256 + tid;
            int row = lin >> 5;
            int c = lin & 31;
            f4 v = *(const f4*)(convw + row * DD + d0 + c * 4);
            *(unsigned long long*)(cw_l + row * 136 + c * 4) = pack4(v[0], v[1], v[2], v[3]);
        }
        // stage x chunk transposed [64 p][128 d]: thread = (d-quad, p-quad)
#pragma unroll
        for (int i = 0; i < 2; ++i) {
            int lin = i * 256 + tid;
            int dq = lin >> 4;   // 0..31 -> d = d0 + dq*4
            int pq = lin & 15;
            const float* xp = xb + (size_t)(d0 + dq * 4) * TR + p0 + pq * 4;
            f4 a0 = *(const f4*)(xp);
            f4 a1 = *(const f4*)(xp + TR);
            f4 a2 = *(const f4*)(xp + 2 * TR);
            f4 a3 = *(const f4*)(xp + 3 * TR);
#pragma unroll
            for (int jj = 0; jj < 4; ++jj) {
                int j = (jj + pq) & 3;  // stagger to spread banks
                *(unsigned long long*)(xT_l + (pq * 4 + j) * 136 + dq * 4) =
                    pack4(a0[j], a1[j], a2[j], a3[j]);
            }
        }
        __syncthreads();
#pragma unroll
        for (int ks = 0; ks < 4; ++ks) {
            int off = ks * 32 + quad * 8;
            s8 af = *(const s8*)(cw_l + (wv * 16 + l15) * 136 + off);
#pragma unroll
            for (int t = 0; t < 4; ++t) {
                s8 bfr = *(const s8*)(xT_l + (t * 16 + l15) * 136 + off);
                acc[t] = __builtin_amdgcn_mfma_f32_16x16x32_bf16(af, bfr, acc[t], 0, 0, 0);
            }
        }
    }
    __syncthreads();
    // dump C/D frags to sm[k][p]: col=lane&15 (p), row=quad*4+reg (k)
#pragma unroll
    for (int t = 0; t < 4; ++t)
#pragma unroll
        for (int r = 0; r < 4; ++r)
            sm[(wv * 16 + quad * 4 + r) * 68 + t * 16 + l15] = acc[t][r];
    __syncthreads();

    // parallel softmax over k per column p: wave wv owns k in [wv*16, wv*16+16)
    // red buffers aliased onto cw_l (dead after last MFMA)
    float* redM = (float*)cw_l;          // [4][64]
    float* redS = ((float*)cw_l) + 256;  // [4][64]
    const int p = lane;
    float mx = -1e30f;
#pragma unroll
    for (int i = 0; i < 16; ++i) mx = fmaxf(mx, sm[(wv * 16 + i) * 68 + p]);
    redM[wv * 64 + p] = mx;
    __syncthreads();
    mx = fmaxf(fmaxf(redM[p], redM[64 + p]), fmaxf(redM[128 + p], redM[192 + p]));
    float s = 0.f;
#pragma unroll
    for (int i = 0; i < 16; ++i) {
        float e = __expf(sm[(wv * 16 + i) * 68 + p] - mx);
        sm[(wv * 16 + i) * 68 + p] = e;
        s += e;
    }
    redS[wv * 64 + p] = s;
    __syncthreads();
    float tot = redS[p] + redS[64 + p] + redS[128 + p] + redS[192 + p];
    const int tt = (p0 + p) / RR;
    const float inv = (float)mask[b * TT + tt] / tot;
    // scale + per-k wave-reduced asum
#pragma unroll
    for (int i = 0; i < 16; ++i) {
        float v = sm[(wv * 16 + i) * 68 + p] * inv;
        sm[(wv * 16 + i) * 68 + p] = v;
        float r = v;
#pragma unroll
        for (int off = 32; off > 0; off >>= 1) r += __shfl_down(r, off, 64);
        if (lane == 0) atomicAdd(&asum[b * 64 + wv * 16 + i], r);
    }
    __syncthreads();
    // write assign bf16 [k][p]
#pragma unroll
    for (int i = 0; i < 4; ++i) {
        int lin = i * 256 + tid;
        int kr = lin >> 4;
        int pq = lin & 15;
        f4 v = *(const f4*)(sm + kr * 68 + pq * 4);
        *(unsigned long long*)(assign + (size_t)(b * 64 + kr) * TR + p0 + pq * 4) =
            pack4(v[0], v[1], v[2], v[3]);
    }
}

// ---------------------------------------------------------------------------
// kB: vladP[ph][b,k,d] = sum_{p in half} assign[k][p]*x[d][p]  (MFMA bf16)
// part 0 additionally subtracts asum*centroid. grid 32*8*2, block 256.
// ---------------------------------------------------------------------------
__global__ __launch_bounds__(256) void kB(const float* __restrict__ x,
                                          const unsigned short* __restrict__ assign,
                                          const float* __restrict__ asum,
                                          const float* __restrict__ cent,
                                          float* __restrict__ vladP) {
    __shared__ unsigned short as_l[64 * 72];  // [k][p-chunk 64 + pad]
    __shared__ unsigned short x_l[64 * 72];   // [d][p-chunk 64 + pad]

    const int blk = blockIdx.x;
    const int b = blk >> 4;
    const int ds = (blk >> 1) & 7;
    const int ph = blk & 1;
    const int d0 = ds * 64;
    const int tid = threadIdx.x;
    const int lane = tid & 63;
    const int wv = tid >> 6;
    const int quad = lane >> 4;
    const int l15 = lane & 15;

    f4 acc[4];
#pragma unroll
    for (int t = 0; t < 4; ++t) acc[t] = (f4){0.f, 0.f, 0.f, 0.f};

    const int pcs = ph ? 25 : 0;
    const int pce = ph ? 49 : 25;
    for (int pc = pcs; pc < pce; ++pc) {
        const int p0 = pc * 64;
        __syncthreads();
        // assign (already bf16): direct 16B copies
#pragma unroll
        for (int i = 0; i < 2; ++i) {
            int lin = i * 256 + tid;
            int row = lin >> 3;
            int c = lin & 7;
            *(s8*)(as_l + row * 72 + c * 8) =
                *(const s8*)(assign + (size_t)(b * 64 + row) * TR + p0 + c * 8);
        }
        // x fp32 -> bf16, natural [d][p]
#pragma unroll
        for (int i = 0; i < 4; ++i) {
            int lin = i * 256 + tid;
            int row = lin >> 4;
            int c = lin & 15;
            f4 v = *(const f4*)(x + (size_t)(b * DD + d0 + row) * TR + p0 + c * 4);
            *(unsigned long long*)(x_l + row * 72 + c * 4) = pack4(v[0], v[1], v[2], v[3]);
        }
        __syncthreads();
#pragma unroll
        for (int ks = 0; ks < 2; ++ks) {
            int off = ks * 32 + quad * 8;
            s8 af = *(const s8*)(as_l + (wv * 16 + l15) * 72 + off);
#pragma unroll
            for (int t = 0; t < 4; ++t) {
                s8 bfr = *(const s8*)(x_l + (t * 16 + l15) * 72 + off);
                acc[t] = __builtin_amdgcn_mfma_f32_16x16x32_bf16(af, bfr, acc[t], 0, 0, 0);
            }
        }
    }
    float* vp = vladP + (size_t)ph * (BB * KK * DD);
#pragma unroll
    for (int r = 0; r < 4; ++r) {
        const int k = wv * 16 + quad * 4 + r;
        float corr = ph ? 0.f : asum[b * 64 + k];
#pragma unroll
        for (int t = 0; t < 4; ++t) {
            const int d = d0 + t * 16 + l15;
            float v = acc[t][r];
            if (!ph) v -= corr * cent[k * DD + d];
            vp[(size_t)(b * 64 + k) * DD + d] = v;
        }
    }
}

// ---------------------------------------------------------------------------
// kC1: per-row sum of squares of (P0+P1). grid 32*8, block 256 (8 rows x 32 thr)
// ---------------------------------------------------------------------------
__global__ __launch_bounds__(256) void kC1(const float* __restrict__ vladP,
                                           float* __restrict__ ss) {
    const int blk = blockIdx.x;
    const int b = blk >> 3;
    const int ks = blk & 7;
    const int tid = threadIdx.x;
    const int kr = tid >> 5;
    const int l32 = tid & 31;
    const int k = ks * 8 + kr;
    const float* q0 = vladP + (size_t)(b * 64 + k) * DD;
    const float* q1 = q0 + (size_t)BB * KK * DD;
    float s = 0.f;
#pragma unroll
    for (int i = 0; i < 4; ++i) {
        f4 a = *(const f4*)(q0 + i * 128 + l32 * 4);
        f4 c = *(const f4*)(q1 + i * 128 + l32 * 4);
#pragma unroll
        for (int j = 0; j < 4; ++j) { float v = a[j] + c[j]; s = fmaf(v, v, s); }
    }
    for (int off = 16; off > 0; off >>= 1) s += __shfl_down(s, off, 32);
    if (l32 == 0) ss[b * 64 + k] = s;
}

// ---------------------------------------------------------------------------
// kC2: scales = intra*global norm; write vlad_n bf16. grid 32*8, block 256.
// ---------------------------------------------------------------------------
__global__ __launch_bounds__(256) void kC2(const float* __restrict__ vladP,
                                           const float* __restrict__ ss,
                                           unsigned short* __restrict__ vn) {
    __shared__ float sc[64];
    const int blk = blockIdx.x;
    const int b = blk >> 3;
    const int js = blk & 7;
    const int tid = threadIdx.x;
    if (tid < 64) {
        float rn = sqrtf(ss[b * 64 + tid]);
        float inv = 1.f / fmaxf(rn, 1e-12f);
        float cb = rn * inv; cb = cb * cb;
        float g = cb;
        for (int off = 32; off > 0; off >>= 1) g += __shfl_down(g, off, 64);
        g = __shfl(g, 0, 64);
        float gi = 1.f / fmaxf(sqrtf(g), 1e-12f);
        sc[tid] = inv * gi;
    }
    __syncthreads();
    const float* q0 = vladP + (size_t)b * KD;
    const float* q1 = q0 + (size_t)BB * KD;
#pragma unroll
    for (int it = 0; it < 4; ++it) {
        int j = js * 4096 + it * 1024 + tid * 4;
        f4 a = *(const f4*)(q0 + j);
        f4 c = *(const f4*)(q1 + j);
        float scl = sc[j >> 9];
        *(unsigned long long*)(vn + (size_t)b * KD + j) =
            pack4((a[0] + c[0]) * scl, (a[1] + c[1]) * scl,
                  (a[2] + c[2]) * scl, (a[3] + c[3]) * scl);
    }
}

// ---------------------------------------------------------------------------
// kD: y[b,o] += vlad_n @ red_w^T (MFMA bf16, red_w converted in staging)
// grid 16 o-tiles * 16 j-splits, block 256. atomicAdd fp32 into y.
// ---------------------------------------------------------------------------
__global__ __launch_bounds__(256) void kD(const unsigned short* __restrict__ vn,
                                          const float* __restrict__ redw,
                                          float* __restrict__ y) {
    __shared__ unsigned short rw_l[64 * 264];  // [o][j-chunk 256 + pad]
    __shared__ unsigned short vl_l[32 * 264];  // [b][j-chunk 256 + pad]

    const int blk = blockIdx.x;
    const int ot = blk & 15;
    const int js = blk >> 4;
    const int o0 = ot * 64;
    const int jb = js * 2048;
    const int tid = threadIdx.x;
    const int lane = tid & 63;
    const int wv = tid >> 6;
    const int quad = lane >> 4;
    const int l15 = lane & 15;

    f4 acc[2];
    acc[0] = (f4){0.f, 0.f, 0.f, 0.f};
    acc[1] = (f4){0.f, 0.f, 0.f, 0.f};

    for (int jc = 0; jc < 8; ++jc) {
        const int j0 = jb + jc * 256;
        __syncthreads();
#pragma unroll
        for (int i = 0; i < 16; ++i) {
            int lin = i * 256 + tid;
            int row = lin >> 6;
            int c = lin & 63;
            f4 v = *(const f4*)(redw + (size_t)(o0 + row) * KD + j0 + c * 4);
            *(unsigned long long*)(rw_l + row * 264 + c * 4) = pack4(v[0], v[1], v[2], v[3]);
        }
#pragma unroll
        for (int i = 0; i < 4; ++i) {
            int lin = i * 256 + tid;
            int row = lin >> 5;
            int c = lin & 31;
            *(s8*)(vl_l + row * 264 + c * 8) =
                *(const s8*)(vn + (size_t)row * KD + j0 + c * 8);
        }
        __syncthreads();
#pragma unroll
        for (int ks = 0; ks < 8; ++ks) {
            int off = ks * 32 + quad * 8;
            s8 bfr = *(const s8*)(rw_l + (wv * 16 + l15) * 264 + off);
#pragma unroll
            for (int t = 0; t < 2; ++t) {
                s8 af = *(const s8*)(vl_l + (t * 16 + l15) * 264 + off);
                acc[t] = __builtin_amdgcn_mfma_f32_16x16x32_bf16(af, bfr, acc[t], 0, 0, 0);
            }
        }
    }
#pragma unroll
    for (int t = 0; t < 2; ++t)
#pragma unroll
        for (int r = 0; r < 4; ++r) {
            int bq = t * 16 + quad * 4 + r;
            int o = o0 + wv * 16 + l15;
            atomicAdd(&y[(size_t)bq * OUTN + o], acc[t][r]);
        }
}

// ---------------------------------------------------------------------------
// kE: LayerNorm over OUT per b -> d_out. grid 32, block 256.
// ---------------------------------------------------------------------------
__global__ __launch_bounds__(256) void kE(const float* __restrict__ y,
                                          const float* __restrict__ gamma,
                                          const float* __restrict__ beta,
                                          float* __restrict__ out) {
    __shared__ float s1s[4], s2s[4];
    __shared__ float mu_s, rstd_s;

    const int b = blockIdx.x;
    const int tid = threadIdx.x;
    const int wave = tid >> 6;
    const int lane = tid & 63;

    f4 v = *(const f4*)(y + (size_t)b * OUTN + tid * 4);
    float s1 = v[0] + v[1] + v[2] + v[3];
    float s2 = v[0] * v[0] + v[1] * v[1] + v[2] * v[2] + v[3] * v[3];
    for (int off = 32; off > 0; off >>= 1) {
        s1 += __shfl_down(s1, off, 64);
        s2 += __shfl_down(s2, off, 64);
    }
    if (lane == 0) { s1s[wave] = s1; s2s[wave] = s2; }
    __syncthreads();
    if (tid == 0) {
        float S1 = s1s[0] + s1s[1] + s1s[2] + s1s[3];
        float S2 = s2s[0] + s2s[1] + s2s[2] + s2s[3];
        float mu = S1 / (float)OUTN;
        float var = S2 / (float)OUTN - mu * mu;
        mu_s = mu;
        rstd_s = 1.0f / sqrtf(var + 1e-5f);
    }
    __syncthreads();
    const float mu = mu_s, rstd = rstd_s;
    f4 g = *(const f4*)(gamma + tid * 4);
    f4 be = *(const f4*)(beta + tid * 4);
    f4 o;
#pragma unroll
    for (int i = 0; i < 4; ++i) o[i] = (v[i] - mu) * rstd * g[i] + be[i];
    *(f4*)(out + (size_t)b * OUTN + tid * 4) = o;
}

// ---------------------------------------------------------------------------
extern "C" void kernel_launch(void* const* d_in, const int* in_sizes, int n_in,
                              void* d_out, int out_size, void* d_ws, size_t ws_size,
                              hipStream_t stream) {
    const float* x     = (const float*)d_in[0];
    const int*   mask  = (const int*)d_in[1];
    const float* cent  = (const float*)d_in[2];
    const float* convw = (const float*)d_in[3];
    const float* redw  = (const float*)d_in[4];
    const float* gam   = (const float*)d_in[5];
    const float* bet   = (const float*)d_in[6];
    float* out = (float*)d_out;
    char* w = (char*)d_ws;

    unsigned short* assign = (unsigned short*)(w + OFF_ASSIGN);
    float*          vladP  = (float*)(w + OFF_VLADP);
    unsigned short* vn     = (unsigned short*)(w + OFF_VN);
    float*          ss     = (float*)(w + OFF_SS);
    float*          asum   = (float*)(w + OFF_ASUM);
    float*          y      = (float*)(w + OFF_Y);

    hipMemsetAsync(asum, 0, 64 * BB * sizeof(float), stream);
    hipMemsetAsync(y, 0, BB * OUTN * sizeof(float), stream);

    kA<<<BB * 49, 256, 0, stream>>>(x, mask, convw, assign, asum);
    kB<<<BB * 8 * 2, 256, 0, stream>>>(x, assign, asum, cent, vladP);
    kC1<<<BB * 8, 256, 0, stream>>>(vladP, ss);
    kC2<<<BB * 8, 256, 0, stream>>>(vladP, ss, vn);
    kD<<<16 * 16, 256, 0, stream>>>(vn, redw, y);
    kE<<<BB, 256, 0, stream>>>(y, gam, bet, out);
}